// Round 7
// baseline (266.370 us; speedup 1.0000x reference)
//
#include <hip/hip_runtime.h>
#include <stdint.h>

// Problem constants
static constexpr int CB = 2, CT = 2048, CD = 1024, CH = 16, CDh = 64, CV = 32000;
static constexpr int CM = CB * CT;  // 4096 token rows

typedef float f32x4 __attribute__((ext_vector_type(4)));
typedef float f32x16 __attribute__((ext_vector_type(16)));
typedef short s16x8 __attribute__((ext_vector_type(8)));
typedef unsigned u32x2 __attribute__((ext_vector_type(2)));

__device__ __forceinline__ unsigned short f2bf(float f) {
  unsigned u = __builtin_bit_cast(unsigned, f);
  unsigned r = 0x7FFFu + ((u >> 16) & 1u);
  return (unsigned short)((u + r) >> 16);
}
__device__ __forceinline__ float bf2f(unsigned short h) {
  unsigned u = ((unsigned)h) << 16;
  return __builtin_bit_cast(float, u);
}
// pack two fp32 -> bf16x2 (low=a, high=b) with round-half-up in 3 VALU ops
__device__ __forceinline__ unsigned pkrh(float a, float b) {
  unsigned ua = __builtin_bit_cast(unsigned, a) + 0x8000u;
  unsigned ub = __builtin_bit_cast(unsigned, b) + 0x8000u;
  return __builtin_amdgcn_perm(ub, ua, 0x07060302);
}
__device__ __forceinline__ void lds_cp16(const void* g, void* l) {
  __builtin_amdgcn_global_load_lds(
      (const __attribute__((address_space(1))) unsigned*)g,
      (__attribute__((address_space(3))) unsigned*)l, 16, 0, 0);
}

// ---------------- kWTA gains (zeroing + bincount fused; pot==0 => top5 = count desc, idx asc) ----
__device__ __forceinline__ void chain5(unsigned n, unsigned& b0, unsigned& b1, unsigned& b2,
                                       unsigned& b3, unsigned& b4) {
  unsigned t;
  t = b0 > n ? b0 : n; n = b0 > n ? n : b0; b0 = t;
  t = b1 > n ? b1 : n; n = b1 > n ? n : b1; b1 = t;
  t = b2 > n ? b2 : n; n = b2 > n ? n : b2; b2 = t;
  t = b3 > n ? b3 : n; n = b3 > n ? n : b3; b3 = t;
  b4 = b4 > n ? b4 : n;
}

__global__ __launch_bounds__(1024) void nsr_gains(const int* __restrict__ ids,
                                                  int* __restrict__ bins,
                                                  float* __restrict__ gains) {
  __shared__ unsigned l5[5120];
  __shared__ unsigned w5[320];
  __shared__ unsigned fin[5];
  int tid = threadIdx.x;
  for (int i = tid; i < CV; i += 1024) bins[i] = 0;
  __syncthreads();
#pragma unroll
  for (int i = 0; i < 4; ++i) atomicAdd(&bins[ids[i * 1024 + tid]], 1);
  __syncthreads();
  unsigned b0 = 0, b1 = 0, b2 = 0, b3 = 0, b4 = 0;
  for (int i = tid; i < CV; i += 1024) {
    unsigned key = (((unsigned)bins[i]) << 15) | (unsigned)(32767 - i);
    chain5(key, b0, b1, b2, b3, b4);
  }
  l5[tid] = b0; l5[1024 + tid] = b1; l5[2048 + tid] = b2; l5[3072 + tid] = b3; l5[4096 + tid] = b4;
  __syncthreads();
  if (tid < 64) {
    unsigned c0 = 0, c1 = 0, c2 = 0, c3 = 0, c4 = 0;
    for (int i = tid; i < 5120; i += 64) chain5(l5[i], c0, c1, c2, c3, c4);
    w5[tid] = c0; w5[64 + tid] = c1; w5[128 + tid] = c2; w5[192 + tid] = c3; w5[256 + tid] = c4;
  }
  __syncthreads();
  if (tid == 0) {
    unsigned c0 = 0, c1 = 0, c2 = 0, c3 = 0, c4 = 0;
    for (int i = 0; i < 320; ++i) chain5(w5[i], c0, c1, c2, c3, c4);
    fin[0] = c0; fin[1] = c1; fin[2] = c2; fin[3] = c3; fin[4] = c4;
  }
  __syncthreads();
  {
    int cnt = bins[tid];
    float g = cnt > 0 ? 0.6f : 1.0f;
    unsigned key = (((unsigned)cnt) << 15) | (unsigned)(32767 - tid);
    if (key == fin[0] || key == fin[1] || key == fin[2] || key == fin[3] || key == fin[4])
      g = 1.5f;
    gains[tid] = g;
  }
}

// ---------------- fused: weights fp32->bf16 (blocks 0-4095) + token-shift mix (4096-8191) ----
__device__ __forceinline__ unsigned short mix1(float tm, float g, float xc, float px) {
  float m = tm * g;
  return f2bf(m * xc + (1.f - m) * px);
}

__global__ void nsr_cvtw_mix(const float* __restrict__ Wr, const float* __restrict__ Wk,
                             const float* __restrict__ Wv, const float* __restrict__ Wo,
                             unsigned short* __restrict__ dst, const float* __restrict__ x,
                             const float* __restrict__ gains, const float* __restrict__ tmr,
                             const float* __restrict__ tmk, const float* __restrict__ tmv,
                             unsigned short* __restrict__ xr, unsigned short* __restrict__ xk,
                             unsigned short* __restrict__ xv) {
  int bid = blockIdx.x;
  if (bid < 4096) {
    int i = bid * 256 + threadIdx.x;
    int which = i >> 18;
    int j = (i & 0x3FFFF) << 2;
    const float* s = which == 0 ? Wr : which == 1 ? Wk : which == 2 ? Wv : Wo;
    float4 v = *(const float4*)(s + j);
    ushort4 o = make_ushort4(f2bf(v.x), f2bf(v.y), f2bf(v.z), f2bf(v.w));
    *(ushort4*)(dst + (size_t)which * (CD * CD) + j) = o;
  } else {
    int i = (bid - 4096) * 256 + threadIdx.x;
    int m = i >> 8;
    int d = (i & 255) << 2;
    int t = m & (CT - 1);
    size_t base = (size_t)m * CD + d;
    float4 xc = *(const float4*)(x + base);
    float4 px = make_float4(0.f, 0.f, 0.f, 0.f);
    if (t > 0) px = *(const float4*)(x + base - CD);
    float4 g = *(const float4*)(gains + d);
    float4 ar = *(const float4*)(tmr + d);
    float4 ak = *(const float4*)(tmk + d);
    float4 av = *(const float4*)(tmv + d);
    *(ushort4*)(xr + base) = make_ushort4(mix1(ar.x, g.x, xc.x, px.x), mix1(ar.y, g.y, xc.y, px.y),
                                          mix1(ar.z, g.z, xc.z, px.z), mix1(ar.w, g.w, xc.w, px.w));
    *(ushort4*)(xk + base) = make_ushort4(mix1(ak.x, g.x, xc.x, px.x), mix1(ak.y, g.y, xc.y, px.y),
                                          mix1(ak.z, g.z, xc.z, px.z), mix1(ak.w, g.w, xc.w, px.w));
    *(ushort4*)(xv + base) = make_ushort4(mix1(av.x, g.x, xc.x, px.x), mix1(av.y, g.y, xc.y, px.y),
                                          mix1(av.z, g.z, xc.z, px.z), mix1(av.w, g.w, xc.w, px.w));
  }
}

// ---------------- shared 128x128 NT-GEMM core (m97 structure, XOR-swizzled LDS) ----
// Klen = contraction length staged, ld = row stride of A/W in elements.
__device__ __forceinline__ void gemm128(const unsigned short* __restrict__ A,
                                        const unsigned short* __restrict__ W, int m0, int n0,
                                        int Klen, int ld, int tid, f32x4 acc[4][4],
                                        unsigned short* As, unsigned short* Bs) {
  const f32x4 fz = {0.f, 0.f, 0.f, 0.f};
  int lane = tid & 63, w = tid >> 6;
  int wm = (w >> 1) << 6, wn = (w & 1) << 6;
  int l15 = lane & 15, quad = lane >> 4;
#pragma unroll
  for (int mt = 0; mt < 4; ++mt)
#pragma unroll
    for (int nt = 0; nt < 4; ++nt) acc[mt][nt] = fz;
  for (int k0 = 0; k0 < Klen; k0 += 32) {
#pragma unroll
    for (int i = 0; i < 2; ++i) {
      int chunk = i * 256 + tid;
      int r = chunk >> 2, cp = chunk & 3, c = cp ^ (r & 3);
      lds_cp16(A + (size_t)(m0 + r) * ld + k0 + c * 8, &As[(chunk & ~63) << 3]);
      lds_cp16(W + (size_t)(n0 + r) * ld + k0 + c * 8, &Bs[(chunk & ~63) << 3]);
    }
    __syncthreads();
    s16x8 af[4], bf[4];
#pragma unroll
    for (int mt = 0; mt < 4; ++mt) {
      int row = wm + mt * 16 + l15;
      af[mt] = *(const s16x8*)&As[row * 32 + ((quad ^ (row & 3)) << 3)];
    }
#pragma unroll
    for (int nt = 0; nt < 4; ++nt) {
      int row = wn + nt * 16 + l15;
      bf[nt] = *(const s16x8*)&Bs[row * 32 + ((quad ^ (row & 3)) << 3)];
    }
#pragma unroll
    for (int mt = 0; mt < 4; ++mt)
#pragma unroll
      for (int nt = 0; nt < 4; ++nt)
        acc[mt][nt] = __builtin_amdgcn_mfma_f32_16x16x32_bf16(af[mt], bf[nt], acc[mt][nt], 0, 0, 0);
    __syncthreads();
  }
}

// fused r/k/v projections; which==2 (v) writes TRANSPOSED vt[B,H,Dh,T] via LDS tile
__global__ __launch_bounds__(256) void nsr_proj(const unsigned short* __restrict__ xr,
                                                const unsigned short* __restrict__ xk,
                                                const unsigned short* __restrict__ xv,
                                                const unsigned short* __restrict__ Wb,
                                                unsigned short* __restrict__ r,
                                                unsigned short* __restrict__ k,
                                                unsigned short* __restrict__ vt) {
  __shared__ alignas(16) unsigned short As[128 * 32];
  __shared__ alignas(16) unsigned short Bs[128 * 32];
  __shared__ alignas(16) unsigned short vts[128 * 136];  // padded C^T tile for v
  int bid = blockIdx.x;
  int which = bid >> 8;
  int bl = bid & 255;
  int m0 = (bl >> 3) << 7, n0 = (bl & 7) << 7;
  const unsigned short* A = which == 0 ? xr : which == 1 ? xk : xv;
  const unsigned short* W = Wb + (size_t)which * (CD * CD);
  f32x4 acc[4][4];
  gemm128(A, W, m0, n0, CD, CD, threadIdx.x, acc, As, Bs);
  int tid = threadIdx.x;
  int lane = tid & 63, w = tid >> 6;
  int wm = (w >> 1) << 6, wn = (w & 1) << 6;
  int l15 = lane & 15, quad = lane >> 4;
  if (which < 2) {
    unsigned short* out = which == 0 ? r : k;
#pragma unroll
    for (int mt = 0; mt < 4; ++mt)
#pragma unroll
      for (int nt = 0; nt < 4; ++nt)
#pragma unroll
        for (int rr = 0; rr < 4; ++rr) {
          int grow = m0 + wm + mt * 16 + quad * 4 + rr;
          int gcol = n0 + wn + nt * 16 + l15;
          float val = acc[mt][nt][rr];
          if (which == 1) val = val > 0.5f ? 1.0f : 0.0f;  // spike forward
          out[(size_t)grow * CD + gcol] = f2bf(val);
        }
  } else {
    // stage C^T into vts[d_local][t_local] (stride 136: 2-way-free b64 writes)
#pragma unroll
    for (int mt = 0; mt < 4; ++mt)
#pragma unroll
      for (int nt = 0; nt < 4; ++nt) {
        int gcl = wn + nt * 16 + l15;       // d-local 0..127
        int gr = wm + mt * 16 + quad * 4;   // t-local, multiple of 4
        unsigned lo = pkrh(acc[mt][nt][0], acc[mt][nt][1]);
        unsigned hi = pkrh(acc[mt][nt][2], acc[mt][nt][3]);
        uint2 pk = make_uint2(lo, hi);
        *(uint2*)&vts[gcl * 136 + gr] = pk;
      }
    __syncthreads();
    // coalesced write-out: 16 lanes cover one full 256B vt row per instruction
    int b2 = m0 >> 11, t0 = m0 & (CT - 1);
    int ch = tid & 15, dl2 = tid >> 4;  // ch: t-chunk 0..15, dl2: d 0..15
#pragma unroll
    for (int rr2 = 0; rr2 < 8; ++rr2) {
      int dloc = rr2 * 16 + dl2;
      int h = (n0 + dloc) >> 6, dl = (n0 + dloc) & 63;
      s16x8 val = *(const s16x8*)&vts[dloc * 136 + ch * 8];
      size_t ob = ((size_t)((b2 * CH + h) * CDh + dl)) * CT + t0 + ch * 8;
      *(s16x8*)(vt + ob) = val;
    }
  }
}

// ---------------- fused attention + sigmoid gating (S^T formulation, q-tile 128) --------
// 8 waves: qh = w&3 (32-q subtile), kq2 = w>>2 (key half). S^T = K·Q^T (32x32x16).
// C->B transform via v_permlane32_swap_b32 (gfx950): swap(P01,P45) = {br0, br2}.
__global__ __launch_bounds__(512, 2) void nsr_attn(const unsigned short* __restrict__ rbf,
                                                   const unsigned short* __restrict__ kbf,
                                                   const unsigned short* __restrict__ vt,
                                                   unsigned short* __restrict__ gated) {
  __shared__ alignas(16) unsigned char smem[32768];
  __shared__ float denp[2][128];
  unsigned short* Ks = (unsigned short*)smem;            // 16KB [128 key][64 d] swizzled
  unsigned short* Vs = (unsigned short*)(smem + 16384);  // 16KB [64 d][128 key] swizzled
  float* Ored = (float*)smem;  // 32KB overlay [qh(4)][d(64)][q31(32)], used after kt loop

  const f32x16 fz16 = {0.f, 0.f, 0.f, 0.f, 0.f, 0.f, 0.f, 0.f,
                       0.f, 0.f, 0.f, 0.f, 0.f, 0.f, 0.f, 0.f};
  const float EXSC = 0.125f * 1.44269504088896f;  // exp(x/8) = exp2(x*EXSC)
  int bid = blockIdx.x;
  int b = bid & 1, hd = (bid >> 1) & 15, qt = bid >> 5;
  int tid = threadIdx.x, lane = tid & 63, w = tid >> 6;
  int l31 = lane & 31, hbit = lane >> 5;
  int qh = w & 3, kq2 = w >> 2;

  // Q fragments from global, pre-scaled by EXSC in registers
  const unsigned short* qrow = rbf + (size_t)(b * CT + qt * 128 + qh * 32 + l31) * CD + hd * 64;
  s16x8 qfrag[4];
#pragma unroll
  for (int s4 = 0; s4 < 4; ++s4) {
    s16x8 qf = *(const s16x8*)(qrow + s4 * 16 + hbit * 8);
    unsigned* qd = (unsigned*)&qf;
#pragma unroll
    for (int j = 0; j < 4; ++j) {
      float lo = __builtin_bit_cast(float, qd[j] << 16) * EXSC;
      float hi = __builtin_bit_cast(float, qd[j] & 0xFFFF0000u) * EXSC;
      qd[j] = pkrh(lo, hi);
    }
    qfrag[s4] = qf;
  }

  // precomputed LDS fragment addresses (kt-invariant)
  const unsigned short* kap[2][4];
#pragma unroll
  for (int ktile = 0; ktile < 2; ++ktile) {
    int keyrow = kq2 * 64 + ktile * 32 + l31;
#pragma unroll
    for (int s4 = 0; s4 < 4; ++s4) {
      int cp = (s4 * 2 + hbit) ^ (keyrow & 7);
      kap[ktile][s4] = &Ks[keyrow * 64 + cp * 8];
    }
  }
  const unsigned short* vap[2][2][2];
#pragma unroll
  for (int ktile = 0; ktile < 2; ++ktile)
#pragma unroll
    for (int s = 0; s < 2; ++s)
#pragma unroll
      for (int dt = 0; dt < 2; ++dt) {
        int drow = dt * 32 + l31;
        int c = kq2 * 8 + ktile * 4 + s * 2 + hbit;
        int cp = (c & 8) | ((c ^ drow) & 7);
        vap[ktile][s][dt] = &Vs[drow * 128 + cp * 8];
      }

  // precomputed staging pointers (advance by constant stride per kt)
  const unsigned short* kgp[2];
  const unsigned short* vgp[2];
  unsigned short* ldk[2];
  unsigned short* ldv[2];
  {
    const unsigned short* kgbase = kbf + (size_t)(b * CT) * CD + hd * 64;
    const unsigned short* vgbase = vt + (size_t)((b * CH + hd) * CDh) * CT;
#pragma unroll
    for (int i = 0; i < 2; ++i) {
      int L = i * 512 + tid;
      int key = L >> 3, cpk = (L & 7) ^ (key & 7);
      kgp[i] = kgbase + (size_t)key * CD + cpk * 8;
      ldk[i] = &Ks[(L & ~63) << 3];
      int d = L >> 4, cp2 = L & 15, c2 = (cp2 & 8) | ((cp2 ^ d) & 7);
      vgp[i] = vgbase + (size_t)d * CT + c2 * 8;
      ldv[i] = &Vs[(L & ~63) << 3];
    }
  }

  f32x16 o_acc[2];
  o_acc[0] = fz16;
  o_acc[1] = fz16;
  float den0 = 0.f, den1 = 0.f;

  for (int kt = 0; kt < 16; ++kt) {
#pragma unroll
    for (int i = 0; i < 2; ++i) {
      lds_cp16(kgp[i], ldk[i]);
      lds_cp16(vgp[i], ldv[i]);
      kgp[i] += 128 * CD;
      vgp[i] += 128;
    }
    __syncthreads();

#pragma unroll
    for (int ktile = 0; ktile < 2; ++ktile) {
      f32x16 sc = fz16;
#pragma unroll
      for (int s4 = 0; s4 < 4; ++s4)
        sc = __builtin_amdgcn_mfma_f32_32x32x16_bf16(*(const s16x8*)kap[ktile][s4], qfrag[s4], sc,
                                                     0, 0, 0);
#pragma unroll
      for (int s = 0; s < 2; ++s) {
        int rb = 8 * s;
        float p0 = __builtin_amdgcn_exp2f(sc[rb + 0]);
        float p1 = __builtin_amdgcn_exp2f(sc[rb + 1]);
        float p2 = __builtin_amdgcn_exp2f(sc[rb + 2]);
        float p3 = __builtin_amdgcn_exp2f(sc[rb + 3]);
        float p4 = __builtin_amdgcn_exp2f(sc[rb + 4]);
        float p5 = __builtin_amdgcn_exp2f(sc[rb + 5]);
        float p6 = __builtin_amdgcn_exp2f(sc[rb + 6]);
        float p7 = __builtin_amdgcn_exp2f(sc[rb + 7]);
        den0 += (p0 + p1) + (p2 + p3);
        den1 += (p4 + p5) + (p6 + p7);
        unsigned P01 = pkrh(p0, p1), P23 = pkrh(p2, p3);
        unsigned P45 = pkrh(p4, p5), P67 = pkrh(p6, p7);
        unsigned br[4];
#if __has_builtin(__builtin_amdgcn_permlane32_swap)
        // swap lanes32-63 of arg0 with lanes0-31 of arg1:
        // ret.x = {P01.lo, P45.lo} = br0 ; ret.y = {P01.hi, P45.hi} = br2
        u32x2 sw0 = __builtin_amdgcn_permlane32_swap(P01, P45, false, false);
        u32x2 sw1 = __builtin_amdgcn_permlane32_swap(P23, P67, false, false);
        br[0] = sw0.x; br[2] = sw0.y;
        br[1] = sw1.x; br[3] = sw1.y;
#else
        unsigned send0 = hbit ? P01 : P45;
        unsigned send1 = hbit ? P23 : P67;
        unsigned recv0 = (unsigned)__shfl_xor((int)send0, 32);
        unsigned recv1 = (unsigned)__shfl_xor((int)send1, 32);
        br[0] = hbit ? recv0 : P01;
        br[1] = hbit ? recv1 : P23;
        br[2] = hbit ? P45 : recv0;
        br[3] = hbit ? P67 : recv1;
#endif
        s16x8 bfrag = __builtin_bit_cast(s16x8, *(const unsigned(*)[4])br);
        o_acc[0] = __builtin_amdgcn_mfma_f32_32x32x16_bf16(*(const s16x8*)vap[ktile][s][0], bfrag,
                                                           o_acc[0], 0, 0, 0);
        o_acc[1] = __builtin_amdgcn_mfma_f32_32x32x16_bf16(*(const s16x8*)vap[ktile][s][1], bfrag,
                                                           o_acc[1], 0, 0, 0);
      }
    }
    __syncthreads();
  }

  // den: the two lane-halves covered complementary keys
  float den = den0 + den1;
  den += __shfl_xor(den, 32);
  if (hbit == 0) denp[kq2][qh * 32 + l31] = den;
  __syncthreads();
  float rinv = 1.0f / (denp[0][qh * 32 + l31] + denp[1][qh * 32 + l31]);

  // cross-wave O reduction (key-half pairs) through the 32KB Ored overlay
  if (kq2 == 1) {
#pragma unroll
    for (int dt = 0; dt < 2; ++dt)
#pragma unroll
      for (int rr = 0; rr < 16; ++rr) {
        int d = dt * 32 + (rr & 3) + 8 * (rr >> 2) + 4 * hbit;
        Ored[qh * 2048 + d * 32 + l31] = o_acc[dt][rr];
      }
  }
  __syncthreads();
  if (kq2 == 0) {
#pragma unroll
    for (int dt = 0; dt < 2; ++dt)
#pragma unroll
      for (int rr = 0; rr < 16; ++rr) {
        int d = dt * 32 + (rr & 3) + 8 * (rr >> 2) + 4 * hbit;
        int idx = qh * 2048 + d * 32 + l31;
        Ored[idx] = (o_acc[dt][rr] + Ored[idx]) * rinv;
      }
  }
  __syncthreads();

  // coalesced epilogue: sigmoid(r) gating + bf16 store
  int q = tid >> 2, dc = tid & 3;
  size_t grow = (size_t)(b * CT + qt * 128 + q) * CD + hd * 64 + dc * 16;
  s16x8 rv0 = *(const s16x8*)(rbf + grow);
  s16x8 rv1 = *(const s16x8*)(rbf + grow + 8);
  unsigned short outv[16];
#pragma unroll
  for (int i = 0; i < 16; ++i) {
    float o = Ored[(q >> 5) * 2048 + (dc * 16 + i) * 32 + (q & 31)];
    float rv = bf2f(i < 8 ? ((unsigned short*)&rv0)[i] : ((unsigned short*)&rv1)[i - 8]);
    float sig = 1.f / (1.f + __expf(-rv));
    outv[i] = f2bf(sig * o);
  }
  *(s16x8*)(gated + grow) = *(s16x8*)&outv[0];
  *(s16x8*)(gated + grow + 8) = *(s16x8*)&outv[8];
}

// ---------------- output GEMM: out = gated @ Wo^T + bo (fp32), split-K2 + atomicAdd ----
__global__ __launch_bounds__(256) void nsr_out(const unsigned short* __restrict__ gated,
                                               const unsigned short* __restrict__ Wo,
                                               const float* __restrict__ bo,
                                               float* __restrict__ out) {
  __shared__ alignas(16) unsigned short As[128 * 32];
  __shared__ alignas(16) unsigned short Bs[128 * 32];
  int bl = blockIdx.x & 255, kz = blockIdx.x >> 8;
  int m0 = (bl >> 3) << 7, n0 = (bl & 7) << 7;
  f32x4 acc[4][4];
  gemm128(gated + kz * 512, Wo + kz * 512, m0, n0, 512, CD, threadIdx.x, acc, As, Bs);
  int lane = threadIdx.x & 63, w = threadIdx.x >> 6;
  int wm = (w >> 1) << 6, wn = (w & 1) << 6;
  int l15 = lane & 15, quad = lane >> 4;
#pragma unroll
  for (int mt = 0; mt < 4; ++mt)
#pragma unroll
    for (int nt = 0; nt < 4; ++nt)
#pragma unroll
      for (int rr = 0; rr < 4; ++rr) {
        int grow = m0 + wm + mt * 16 + quad * 4 + rr;
        int gcol = n0 + wn + nt * 16 + l15;
        float val = acc[mt][nt][rr] + (kz == 0 ? bo[gcol] : 0.f);
        atomicAdd(&out[(size_t)grow * CD + gcol], val);
      }
}

extern "C" void kernel_launch(void* const* d_in, const int* in_sizes, int n_in,
                              void* d_out, int out_size, void* d_ws, size_t ws_size,
                              hipStream_t stream) {
  const float* x = (const float*)d_in[0];
  const int* ids = (const int*)d_in[1];
  const float* Wr = (const float*)d_in[2];
  const float* Wk = (const float*)d_in[3];
  const float* Wv = (const float*)d_in[4];
  const float* Wo = (const float*)d_in[5];
  const float* bo = (const float*)d_in[6];
  const float* tmk = (const float*)d_in[7];
  const float* tmv = (const float*)d_in[8];
  const float* tmr = (const float*)d_in[9];

  char* ws = (char*)d_ws;
  size_t off = 0;
  int* bins = (int*)(ws + off); off += 131072;
  float* gains = (float*)(ws + off); off += 4096;
  unsigned short* Wb = (unsigned short*)(ws + off); off += (size_t)4 * CD * CD * 2;
  unsigned short* xr = (unsigned short*)(ws + off); off += (size_t)CM * CD * 2;
  unsigned short* xk = (unsigned short*)(ws + off); off += (size_t)CM * CD * 2;
  unsigned short* xv = (unsigned short*)(ws + off); off += (size_t)CM * CD * 2;
  unsigned short* rb = (unsigned short*)(ws + off); off += (size_t)CM * CD * 2;
  unsigned short* kb = (unsigned short*)(ws + off); off += (size_t)CM * CD * 2;
  unsigned short* vtb = (unsigned short*)(ws + off); off += (size_t)CM * CD * 2;
  unsigned short* gatedb = (unsigned short*)(ws + off); off += (size_t)CM * CD * 2;

  nsr_gains<<<1, 1024, 0, stream>>>(ids, bins, gains);
  nsr_cvtw_mix<<<8192, 256, 0, stream>>>(Wr, Wk, Wv, Wo, Wb, x, gains, tmr, tmk, tmv, xr, xk, xv);
  nsr_proj<<<768, 256, 0, stream>>>(xr, xk, xv, Wb, rb, kb, vtb);
  nsr_attn<<<512, 512, 0, stream>>>(rb, kb, vtb, gatedb);
  hipMemsetAsync(d_out, 0, (size_t)CM * CD * sizeof(float), stream);
  nsr_out<<<512, 256, 0, stream>>>(gatedb, Wb + (size_t)3 * CD * CD, bo, (float*)d_out);
}

// Round 8
// 240.961 us; speedup vs baseline: 1.1054x; 1.1054x over previous
//
#include <hip/hip_runtime.h>
#include <stdint.h>

// Problem constants
static constexpr int CB = 2, CT = 2048, CD = 1024, CH = 16, CDh = 64, CV = 32000;
static constexpr int CM = CB * CT;  // 4096 token rows

typedef float f32x4 __attribute__((ext_vector_type(4)));
typedef float f32x16 __attribute__((ext_vector_type(16)));
typedef short s16x8 __attribute__((ext_vector_type(8)));
typedef unsigned u32x2 __attribute__((ext_vector_type(2)));

__device__ __forceinline__ unsigned short f2bf(float f) {
  unsigned u = __builtin_bit_cast(unsigned, f);
  unsigned r = 0x7FFFu + ((u >> 16) & 1u);
  return (unsigned short)((u + r) >> 16);
}
__device__ __forceinline__ float bf2f(unsigned short h) {
  unsigned u = ((unsigned)h) << 16;
  return __builtin_bit_cast(float, u);
}
// pack two fp32 -> bf16x2 (low=a, high=b) with round-half-up in 3 VALU ops
__device__ __forceinline__ unsigned pkrh(float a, float b) {
  unsigned ua = __builtin_bit_cast(unsigned, a) + 0x8000u;
  unsigned ub = __builtin_bit_cast(unsigned, b) + 0x8000u;
  return __builtin_amdgcn_perm(ub, ua, 0x07060302);
}
__device__ __forceinline__ void lds_cp16(const void* g, void* l) {
  __builtin_amdgcn_global_load_lds(
      (const __attribute__((address_space(1))) unsigned*)g,
      (__attribute__((address_space(3))) unsigned*)l, 16, 0, 0);
}

// ---------------- kWTA gains (zeroing + bincount fused; pot==0 => top5 = count desc, idx asc) ----
__device__ __forceinline__ void chain5(unsigned n, unsigned& b0, unsigned& b1, unsigned& b2,
                                       unsigned& b3, unsigned& b4) {
  unsigned t;
  t = b0 > n ? b0 : n; n = b0 > n ? n : b0; b0 = t;
  t = b1 > n ? b1 : n; n = b1 > n ? n : b1; b1 = t;
  t = b2 > n ? b2 : n; n = b2 > n ? n : b2; b2 = t;
  t = b3 > n ? b3 : n; n = b3 > n ? n : b3; b3 = t;
  b4 = b4 > n ? b4 : n;
}

__global__ __launch_bounds__(1024) void nsr_gains(const int* __restrict__ ids,
                                                  int* __restrict__ bins,
                                                  float* __restrict__ gains) {
  __shared__ unsigned l5[5120];
  __shared__ unsigned w5[320];
  __shared__ unsigned fin[5];
  int tid = threadIdx.x;
  for (int i = tid; i < CV; i += 1024) bins[i] = 0;
  __syncthreads();
#pragma unroll
  for (int i = 0; i < 4; ++i) atomicAdd(&bins[ids[i * 1024 + tid]], 1);
  __syncthreads();
  unsigned b0 = 0, b1 = 0, b2 = 0, b3 = 0, b4 = 0;
  for (int i = tid; i < CV; i += 1024) {
    unsigned key = (((unsigned)bins[i]) << 15) | (unsigned)(32767 - i);
    chain5(key, b0, b1, b2, b3, b4);
  }
  l5[tid] = b0; l5[1024 + tid] = b1; l5[2048 + tid] = b2; l5[3072 + tid] = b3; l5[4096 + tid] = b4;
  __syncthreads();
  if (tid < 64) {
    unsigned c0 = 0, c1 = 0, c2 = 0, c3 = 0, c4 = 0;
    for (int i = tid; i < 5120; i += 64) chain5(l5[i], c0, c1, c2, c3, c4);
    w5[tid] = c0; w5[64 + tid] = c1; w5[128 + tid] = c2; w5[192 + tid] = c3; w5[256 + tid] = c4;
  }
  __syncthreads();
  if (tid == 0) {
    unsigned c0 = 0, c1 = 0, c2 = 0, c3 = 0, c4 = 0;
    for (int i = 0; i < 320; ++i) chain5(w5[i], c0, c1, c2, c3, c4);
    fin[0] = c0; fin[1] = c1; fin[2] = c2; fin[3] = c3; fin[4] = c4;
  }
  __syncthreads();
  {
    int cnt = bins[tid];
    float g = cnt > 0 ? 0.6f : 1.0f;
    unsigned key = (((unsigned)cnt) << 15) | (unsigned)(32767 - tid);
    if (key == fin[0] || key == fin[1] || key == fin[2] || key == fin[3] || key == fin[4])
      g = 1.5f;
    gains[tid] = g;
  }
}

// ---------------- fused: weights fp32->bf16 (blocks 0-4095) + token-shift mix (4096-8191) ----
__device__ __forceinline__ unsigned short mix1(float tm, float g, float xc, float px) {
  float m = tm * g;
  return f2bf(m * xc + (1.f - m) * px);
}

__global__ void nsr_cvtw_mix(const float* __restrict__ Wr, const float* __restrict__ Wk,
                             const float* __restrict__ Wv, const float* __restrict__ Wo,
                             unsigned short* __restrict__ dst, const float* __restrict__ x,
                             const float* __restrict__ gains, const float* __restrict__ tmr,
                             const float* __restrict__ tmk, const float* __restrict__ tmv,
                             unsigned short* __restrict__ xr, unsigned short* __restrict__ xk,
                             unsigned short* __restrict__ xv) {
  int bid = blockIdx.x;
  if (bid < 4096) {
    int i = bid * 256 + threadIdx.x;
    int which = i >> 18;
    int j = (i & 0x3FFFF) << 2;
    const float* s = which == 0 ? Wr : which == 1 ? Wk : which == 2 ? Wv : Wo;
    float4 v = *(const float4*)(s + j);
    ushort4 o = make_ushort4(f2bf(v.x), f2bf(v.y), f2bf(v.z), f2bf(v.w));
    *(ushort4*)(dst + (size_t)which * (CD * CD) + j) = o;
  } else {
    int i = (bid - 4096) * 256 + threadIdx.x;
    int m = i >> 8;
    int d = (i & 255) << 2;
    int t = m & (CT - 1);
    size_t base = (size_t)m * CD + d;
    float4 xc = *(const float4*)(x + base);
    float4 px = make_float4(0.f, 0.f, 0.f, 0.f);
    if (t > 0) px = *(const float4*)(x + base - CD);
    float4 g = *(const float4*)(gains + d);
    float4 ar = *(const float4*)(tmr + d);
    float4 ak = *(const float4*)(tmk + d);
    float4 av = *(const float4*)(tmv + d);
    *(ushort4*)(xr + base) = make_ushort4(mix1(ar.x, g.x, xc.x, px.x), mix1(ar.y, g.y, xc.y, px.y),
                                          mix1(ar.z, g.z, xc.z, px.z), mix1(ar.w, g.w, xc.w, px.w));
    *(ushort4*)(xk + base) = make_ushort4(mix1(ak.x, g.x, xc.x, px.x), mix1(ak.y, g.y, xc.y, px.y),
                                          mix1(ak.z, g.z, xc.z, px.z), mix1(ak.w, g.w, xc.w, px.w));
    *(ushort4*)(xv + base) = make_ushort4(mix1(av.x, g.x, xc.x, px.x), mix1(av.y, g.y, xc.y, px.y),
                                          mix1(av.z, g.z, xc.z, px.z), mix1(av.w, g.w, xc.w, px.w));
  }
}

// XCD-aware tile swizzle for 256-block GEMMs: dispatch round-robins bid over 8 XCDs,
// so give each XCD 4 m-tiles x 8 n-tiles -> A m-tile read once per chip into that
// XCD's L2 and reused by its 8 co-resident n-blocks.
__device__ __forceinline__ void swz_tiles(int bl, int& m0, int& n0) {
  int xcd = bl & 7, idx = bl >> 3;
  int mt8 = xcd * 4 + (idx & 3);
  int nt8 = idx >> 2;
  m0 = mt8 << 7;
  n0 = nt8 << 7;
}

// ---------------- shared 128x128 NT-GEMM core (m97 structure, XOR-swizzled LDS) ----
__device__ __forceinline__ void gemm128(const unsigned short* __restrict__ A,
                                        const unsigned short* __restrict__ W, int m0, int n0,
                                        int Klen, int ld, int tid, f32x4 acc[4][4],
                                        unsigned short* As, unsigned short* Bs) {
  const f32x4 fz = {0.f, 0.f, 0.f, 0.f};
  int lane = tid & 63, w = tid >> 6;
  int wm = (w >> 1) << 6, wn = (w & 1) << 6;
  int l15 = lane & 15, quad = lane >> 4;
#pragma unroll
  for (int mt = 0; mt < 4; ++mt)
#pragma unroll
    for (int nt = 0; nt < 4; ++nt) acc[mt][nt] = fz;
  for (int k0 = 0; k0 < Klen; k0 += 32) {
#pragma unroll
    for (int i = 0; i < 2; ++i) {
      int chunk = i * 256 + tid;
      int r = chunk >> 2, cp = chunk & 3, c = cp ^ (r & 3);
      lds_cp16(A + (size_t)(m0 + r) * ld + k0 + c * 8, &As[(chunk & ~63) << 3]);
      lds_cp16(W + (size_t)(n0 + r) * ld + k0 + c * 8, &Bs[(chunk & ~63) << 3]);
    }
    __syncthreads();
    s16x8 af[4], bf[4];
#pragma unroll
    for (int mt = 0; mt < 4; ++mt) {
      int row = wm + mt * 16 + l15;
      af[mt] = *(const s16x8*)&As[row * 32 + ((quad ^ (row & 3)) << 3)];
    }
#pragma unroll
    for (int nt = 0; nt < 4; ++nt) {
      int row = wn + nt * 16 + l15;
      bf[nt] = *(const s16x8*)&Bs[row * 32 + ((quad ^ (row & 3)) << 3)];
    }
#pragma unroll
    for (int mt = 0; mt < 4; ++mt)
#pragma unroll
      for (int nt = 0; nt < 4; ++nt)
        acc[mt][nt] = __builtin_amdgcn_mfma_f32_16x16x32_bf16(af[mt], bf[nt], acc[mt][nt], 0, 0, 0);
    __syncthreads();
  }
}

// fused r/k/v projections; which==2 (v) writes TRANSPOSED vt[B,H,Dh,T] via LDS tile
__global__ __launch_bounds__(256) void nsr_proj(const unsigned short* __restrict__ xr,
                                                const unsigned short* __restrict__ xk,
                                                const unsigned short* __restrict__ xv,
                                                const unsigned short* __restrict__ Wb,
                                                unsigned short* __restrict__ r,
                                                unsigned short* __restrict__ k,
                                                unsigned short* __restrict__ vt) {
  __shared__ alignas(16) unsigned short As[128 * 32];
  __shared__ alignas(16) unsigned short Bs[128 * 32];
  __shared__ alignas(16) unsigned short vts[128 * 136];  // padded C^T tile for v
  int bid = blockIdx.x;
  int which = bid >> 8;
  int m0, n0;
  swz_tiles(bid & 255, m0, n0);
  const unsigned short* A = which == 0 ? xr : which == 1 ? xk : xv;
  const unsigned short* W = Wb + (size_t)which * (CD * CD);
  f32x4 acc[4][4];
  gemm128(A, W, m0, n0, CD, CD, threadIdx.x, acc, As, Bs);
  int tid = threadIdx.x;
  int lane = tid & 63, w = tid >> 6;
  int wm = (w >> 1) << 6, wn = (w & 1) << 6;
  int l15 = lane & 15, quad = lane >> 4;
  if (which < 2) {
    unsigned short* out = which == 0 ? r : k;
#pragma unroll
    for (int mt = 0; mt < 4; ++mt)
#pragma unroll
      for (int nt = 0; nt < 4; ++nt)
#pragma unroll
        for (int rr = 0; rr < 4; ++rr) {
          int grow = m0 + wm + mt * 16 + quad * 4 + rr;
          int gcol = n0 + wn + nt * 16 + l15;
          float val = acc[mt][nt][rr];
          if (which == 1) val = val > 0.5f ? 1.0f : 0.0f;  // spike forward
          out[(size_t)grow * CD + gcol] = f2bf(val);
        }
  } else {
    // stage C^T into vts[d_local][t_local] (stride 136: 2-way-free b64 writes)
#pragma unroll
    for (int mt = 0; mt < 4; ++mt)
#pragma unroll
      for (int nt = 0; nt < 4; ++nt) {
        int gcl = wn + nt * 16 + l15;       // d-local 0..127
        int gr = wm + mt * 16 + quad * 4;   // t-local, multiple of 4
        unsigned lo = pkrh(acc[mt][nt][0], acc[mt][nt][1]);
        unsigned hi = pkrh(acc[mt][nt][2], acc[mt][nt][3]);
        uint2 pk = make_uint2(lo, hi);
        *(uint2*)&vts[gcl * 136 + gr] = pk;
      }
    __syncthreads();
    // coalesced write-out: 16 lanes cover one full 256B vt row per instruction
    int b2 = m0 >> 11, t0 = m0 & (CT - 1);
    int ch = tid & 15, dl2 = tid >> 4;  // ch: t-chunk 0..15, dl2: d 0..15
#pragma unroll
    for (int rr2 = 0; rr2 < 8; ++rr2) {
      int dloc = rr2 * 16 + dl2;
      int h = (n0 + dloc) >> 6, dl = (n0 + dloc) & 63;
      s16x8 val = *(const s16x8*)&vts[dloc * 136 + ch * 8];
      size_t ob = ((size_t)((b2 * CH + h) * CDh + dl)) * CT + t0 + ch * 8;
      *(s16x8*)(vt + ob) = val;
    }
  }
}

// ---------------- fused attention + sigmoid gating (S^T formulation, q-tile 128) --------
// 8 waves: qh = w&3 (32-q subtile), kq2 = w>>2 (key half). S^T = K·Q^T (32x32x16).
// C->B transform via v_permlane32_swap_b32 (gfx950): swap(P01,P45) = {br0, br2}.
__global__ __launch_bounds__(512, 2) void nsr_attn(const unsigned short* __restrict__ rbf,
                                                   const unsigned short* __restrict__ kbf,
                                                   const unsigned short* __restrict__ vt,
                                                   unsigned short* __restrict__ gated) {
  __shared__ alignas(16) unsigned char smem[32768];
  __shared__ float denp[2][128];
  unsigned short* Ks = (unsigned short*)smem;            // 16KB [128 key][64 d] swizzled
  unsigned short* Vs = (unsigned short*)(smem + 16384);  // 16KB [64 d][128 key] swizzled
  float* Ored = (float*)smem;  // 32KB overlay [qh(4)][d(64)][q31(32)], used after kt loop

  const f32x16 fz16 = {0.f, 0.f, 0.f, 0.f, 0.f, 0.f, 0.f, 0.f,
                       0.f, 0.f, 0.f, 0.f, 0.f, 0.f, 0.f, 0.f};
  const float EXSC = 0.125f * 1.44269504088896f;  // exp(x/8) = exp2(x*EXSC)
  int bid = blockIdx.x;
  int b = bid & 1, hd = (bid >> 1) & 15, qt = bid >> 5;
  int tid = threadIdx.x, lane = tid & 63, w = tid >> 6;
  int l31 = lane & 31, hbit = lane >> 5;
  int qh = w & 3, kq2 = w >> 2;

  // Q fragments from global, pre-scaled by EXSC in registers
  const unsigned short* qrow = rbf + (size_t)(b * CT + qt * 128 + qh * 32 + l31) * CD + hd * 64;
  s16x8 qfrag[4];
#pragma unroll
  for (int s4 = 0; s4 < 4; ++s4) {
    s16x8 qf = *(const s16x8*)(qrow + s4 * 16 + hbit * 8);
    unsigned* qd = (unsigned*)&qf;
#pragma unroll
    for (int j = 0; j < 4; ++j) {
      float lo = __builtin_bit_cast(float, qd[j] << 16) * EXSC;
      float hi = __builtin_bit_cast(float, qd[j] & 0xFFFF0000u) * EXSC;
      qd[j] = pkrh(lo, hi);
    }
    qfrag[s4] = qf;
  }

  // precomputed LDS fragment addresses (kt-invariant)
  const unsigned short* kap[2][4];
#pragma unroll
  for (int ktile = 0; ktile < 2; ++ktile) {
    int keyrow = kq2 * 64 + ktile * 32 + l31;
#pragma unroll
    for (int s4 = 0; s4 < 4; ++s4) {
      int cp = (s4 * 2 + hbit) ^ (keyrow & 7);
      kap[ktile][s4] = &Ks[keyrow * 64 + cp * 8];
    }
  }
  const unsigned short* vap[2][2][2];
#pragma unroll
  for (int ktile = 0; ktile < 2; ++ktile)
#pragma unroll
    for (int s = 0; s < 2; ++s)
#pragma unroll
      for (int dt = 0; dt < 2; ++dt) {
        int drow = dt * 32 + l31;
        int c = kq2 * 8 + ktile * 4 + s * 2 + hbit;
        int cp = (c & 8) | ((c ^ drow) & 7);
        vap[ktile][s][dt] = &Vs[drow * 128 + cp * 8];
      }

  // precomputed staging pointers (advance by constant stride per kt)
  const unsigned short* kgp[2];
  const unsigned short* vgp[2];
  unsigned short* ldk[2];
  unsigned short* ldv[2];
  {
    const unsigned short* kgbase = kbf + (size_t)(b * CT) * CD + hd * 64;
    const unsigned short* vgbase = vt + (size_t)((b * CH + hd) * CDh) * CT;
#pragma unroll
    for (int i = 0; i < 2; ++i) {
      int L = i * 512 + tid;
      int key = L >> 3, cpk = (L & 7) ^ (key & 7);
      kgp[i] = kgbase + (size_t)key * CD + cpk * 8;
      ldk[i] = &Ks[(L & ~63) << 3];
      int d = L >> 4, cp2 = L & 15, c2 = (cp2 & 8) | ((cp2 ^ d) & 7);
      vgp[i] = vgbase + (size_t)d * CT + c2 * 8;
      ldv[i] = &Vs[(L & ~63) << 3];
    }
  }

  f32x16 o_acc[2];
  o_acc[0] = fz16;
  o_acc[1] = fz16;
  float den0 = 0.f, den1 = 0.f;

  for (int kt = 0; kt < 16; ++kt) {
#pragma unroll
    for (int i = 0; i < 2; ++i) {
      lds_cp16(kgp[i], ldk[i]);
      lds_cp16(vgp[i], ldv[i]);
      kgp[i] += 128 * CD;
      vgp[i] += 128;
    }
    __syncthreads();

#pragma unroll
    for (int ktile = 0; ktile < 2; ++ktile) {
      f32x16 sc = fz16;
#pragma unroll
      for (int s4 = 0; s4 < 4; ++s4)
        sc = __builtin_amdgcn_mfma_f32_32x32x16_bf16(*(const s16x8*)kap[ktile][s4], qfrag[s4], sc,
                                                     0, 0, 0);
#pragma unroll
      for (int s = 0; s < 2; ++s) {
        int rb = 8 * s;
        float p0 = __builtin_amdgcn_exp2f(sc[rb + 0]);
        float p1 = __builtin_amdgcn_exp2f(sc[rb + 1]);
        float p2 = __builtin_amdgcn_exp2f(sc[rb + 2]);
        float p3 = __builtin_amdgcn_exp2f(sc[rb + 3]);
        float p4 = __builtin_amdgcn_exp2f(sc[rb + 4]);
        float p5 = __builtin_amdgcn_exp2f(sc[rb + 5]);
        float p6 = __builtin_amdgcn_exp2f(sc[rb + 6]);
        float p7 = __builtin_amdgcn_exp2f(sc[rb + 7]);
        den0 += (p0 + p1) + (p2 + p3);
        den1 += (p4 + p5) + (p6 + p7);
        unsigned P01 = pkrh(p0, p1), P23 = pkrh(p2, p3);
        unsigned P45 = pkrh(p4, p5), P67 = pkrh(p6, p7);
        unsigned br[4];
#if __has_builtin(__builtin_amdgcn_permlane32_swap)
        u32x2 sw0 = __builtin_amdgcn_permlane32_swap(P01, P45, false, false);
        u32x2 sw1 = __builtin_amdgcn_permlane32_swap(P23, P67, false, false);
        br[0] = sw0.x; br[2] = sw0.y;
        br[1] = sw1.x; br[3] = sw1.y;
#else
        unsigned send0 = hbit ? P01 : P45;
        unsigned send1 = hbit ? P23 : P67;
        unsigned recv0 = (unsigned)__shfl_xor((int)send0, 32);
        unsigned recv1 = (unsigned)__shfl_xor((int)send1, 32);
        br[0] = hbit ? recv0 : P01;
        br[1] = hbit ? recv1 : P23;
        br[2] = hbit ? P45 : recv0;
        br[3] = hbit ? P67 : recv1;
#endif
        s16x8 bfrag = __builtin_bit_cast(s16x8, *(const unsigned(*)[4])br);
        o_acc[0] = __builtin_amdgcn_mfma_f32_32x32x16_bf16(*(const s16x8*)vap[ktile][s][0], bfrag,
                                                           o_acc[0], 0, 0, 0);
        o_acc[1] = __builtin_amdgcn_mfma_f32_32x32x16_bf16(*(const s16x8*)vap[ktile][s][1], bfrag,
                                                           o_acc[1], 0, 0, 0);
      }
    }
    __syncthreads();
  }

  // den: the two lane-halves covered complementary keys
  float den = den0 + den1;
  den += __shfl_xor(den, 32);
  if (hbit == 0) denp[kq2][qh * 32 + l31] = den;
  __syncthreads();
  float rinv = 1.0f / (denp[0][qh * 32 + l31] + denp[1][qh * 32 + l31]);

  // cross-wave O reduction (key-half pairs) through the 32KB Ored overlay
  if (kq2 == 1) {
#pragma unroll
    for (int dt = 0; dt < 2; ++dt)
#pragma unroll
      for (int rr = 0; rr < 16; ++rr) {
        int d = dt * 32 + (rr & 3) + 8 * (rr >> 2) + 4 * hbit;
        Ored[qh * 2048 + d * 32 + l31] = o_acc[dt][rr];
      }
  }
  __syncthreads();
  if (kq2 == 0) {
#pragma unroll
    for (int dt = 0; dt < 2; ++dt)
#pragma unroll
      for (int rr = 0; rr < 16; ++rr) {
        int d = dt * 32 + (rr & 3) + 8 * (rr >> 2) + 4 * hbit;
        int idx = qh * 2048 + d * 32 + l31;
        Ored[idx] = (o_acc[dt][rr] + Ored[idx]) * rinv;
      }
  }
  __syncthreads();

  // coalesced epilogue: sigmoid(r) gating + bf16 store
  int q = tid >> 2, dc = tid & 3;
  size_t grow = (size_t)(b * CT + qt * 128 + q) * CD + hd * 64 + dc * 16;
  s16x8 rv0 = *(const s16x8*)(rbf + grow);
  s16x8 rv1 = *(const s16x8*)(rbf + grow + 8);
  unsigned short outv[16];
#pragma unroll
  for (int i = 0; i < 16; ++i) {
    float o = Ored[(q >> 5) * 2048 + (dc * 16 + i) * 32 + (q & 31)];
    float rv = bf2f(i < 8 ? ((unsigned short*)&rv0)[i] : ((unsigned short*)&rv1)[i - 8]);
    float sig = 1.f / (1.f + __expf(-rv));
    outv[i] = f2bf(sig * o);
  }
  *(s16x8*)(gated + grow) = *(s16x8*)&outv[0];
  *(s16x8*)(gated + grow + 8) = *(s16x8*)&outv[8];
}

// ---------------- output GEMM: out = gated @ Wo^T + bo (fp32 out) ----------------
__global__ __launch_bounds__(256) void nsr_out(const unsigned short* __restrict__ gated,
                                               const unsigned short* __restrict__ Wo,
                                               const float* __restrict__ bo,
                                               float* __restrict__ out) {
  __shared__ alignas(16) unsigned short As[128 * 32];
  __shared__ alignas(16) unsigned short Bs[128 * 32];
  int m0, n0;
  swz_tiles(blockIdx.x, m0, n0);
  f32x4 acc[4][4];
  gemm128(gated, Wo, m0, n0, CD, CD, threadIdx.x, acc, As, Bs);
  int lane = threadIdx.x & 63, w = threadIdx.x >> 6;
  int wm = (w >> 1) << 6, wn = (w & 1) << 6;
  int l15 = lane & 15, quad = lane >> 4;
#pragma unroll
  for (int mt = 0; mt < 4; ++mt)
#pragma unroll
    for (int nt = 0; nt < 4; ++nt)
#pragma unroll
      for (int rr = 0; rr < 4; ++rr) {
        int grow = m0 + wm + mt * 16 + quad * 4 + rr;
        int gcol = n0 + wn + nt * 16 + l15;
        out[(size_t)grow * CD + gcol] = acc[mt][nt][rr] + bo[gcol];
      }
}

extern "C" void kernel_launch(void* const* d_in, const int* in_sizes, int n_in,
                              void* d_out, int out_size, void* d_ws, size_t ws_size,
                              hipStream_t stream) {
  const float* x = (const float*)d_in[0];
  const int* ids = (const int*)d_in[1];
  const float* Wr = (const float*)d_in[2];
  const float* Wk = (const float*)d_in[3];
  const float* Wv = (const float*)d_in[4];
  const float* Wo = (const float*)d_in[5];
  const float* bo = (const float*)d_in[6];
  const float* tmk = (const float*)d_in[7];
  const float* tmv = (const float*)d_in[8];
  const float* tmr = (const float*)d_in[9];

  char* ws = (char*)d_ws;
  size_t off = 0;
  int* bins = (int*)(ws + off); off += 131072;
  float* gains = (float*)(ws + off); off += 4096;
  unsigned short* Wb = (unsigned short*)(ws + off); off += (size_t)4 * CD * CD * 2;
  unsigned short* xr = (unsigned short*)(ws + off); off += (size_t)CM * CD * 2;
  unsigned short* xk = (unsigned short*)(ws + off); off += (size_t)CM * CD * 2;
  unsigned short* xv = (unsigned short*)(ws + off); off += (size_t)CM * CD * 2;
  unsigned short* rb = (unsigned short*)(ws + off); off += (size_t)CM * CD * 2;
  unsigned short* kb = (unsigned short*)(ws + off); off += (size_t)CM * CD * 2;
  unsigned short* vtb = (unsigned short*)(ws + off); off += (size_t)CM * CD * 2;
  unsigned short* gatedb = (unsigned short*)(ws + off); off += (size_t)CM * CD * 2;

  nsr_gains<<<1, 1024, 0, stream>>>(ids, bins, gains);
  nsr_cvtw_mix<<<8192, 256, 0, stream>>>(Wr, Wk, Wv, Wo, Wb, x, gains, tmr, tmk, tmv, xr, xk, xv);
  nsr_proj<<<768, 256, 0, stream>>>(xr, xk, xv, Wb, rb, kb, vtb);
  nsr_attn<<<512, 512, 0, stream>>>(rb, kb, vtb, gatedb);
  nsr_out<<<256, 256, 0, stream>>>(gatedb, Wb + (size_t)3 * CD * CD, bo, (float*)d_out);
}

// Round 9
// 225.386 us; speedup vs baseline: 1.1818x; 1.0691x over previous
//
#include <hip/hip_runtime.h>
#include <stdint.h>

// Problem constants
static constexpr int CB = 2, CT = 2048, CD = 1024, CH = 16, CDh = 64, CV = 32000;
static constexpr int CM = CB * CT;  // 4096 token rows

typedef float f32x4 __attribute__((ext_vector_type(4)));
typedef float f32x16 __attribute__((ext_vector_type(16)));
typedef short s16x8 __attribute__((ext_vector_type(8)));
typedef unsigned u32x2 __attribute__((ext_vector_type(2)));

__device__ __forceinline__ unsigned short f2bf(float f) {
  unsigned u = __builtin_bit_cast(unsigned, f);
  unsigned r = 0x7FFFu + ((u >> 16) & 1u);
  return (unsigned short)((u + r) >> 16);
}
__device__ __forceinline__ float bf2f(unsigned short h) {
  unsigned u = ((unsigned)h) << 16;
  return __builtin_bit_cast(float, u);
}
// pack two fp32 -> bf16x2 (low=a, high=b) with round-half-up in 3 VALU ops
__device__ __forceinline__ unsigned pkrh(float a, float b) {
  unsigned ua = __builtin_bit_cast(unsigned, a) + 0x8000u;
  unsigned ub = __builtin_bit_cast(unsigned, b) + 0x8000u;
  return __builtin_amdgcn_perm(ub, ua, 0x07060302);
}
__device__ __forceinline__ void lds_cp16(const void* g, void* l) {
  __builtin_amdgcn_global_load_lds(
      (const __attribute__((address_space(1))) unsigned*)g,
      (__attribute__((address_space(3))) unsigned*)l, 16, 0, 0);
}

// ---------------- kWTA gains (zeroing + bincount fused; pot==0 => top5 = count desc, idx asc) ----
__device__ __forceinline__ void chain5(unsigned n, unsigned& b0, unsigned& b1, unsigned& b2,
                                       unsigned& b3, unsigned& b4) {
  unsigned t;
  t = b0 > n ? b0 : n; n = b0 > n ? n : b0; b0 = t;
  t = b1 > n ? b1 : n; n = b1 > n ? n : b1; b1 = t;
  t = b2 > n ? b2 : n; n = b2 > n ? n : b2; b2 = t;
  t = b3 > n ? b3 : n; n = b3 > n ? n : b3; b3 = t;
  b4 = b4 > n ? b4 : n;
}

__global__ __launch_bounds__(1024) void nsr_gains(const int* __restrict__ ids,
                                                  int* __restrict__ bins,
                                                  float* __restrict__ gains) {
  __shared__ unsigned l5[5120];
  __shared__ unsigned w5[320];
  __shared__ unsigned fin[5];
  int tid = threadIdx.x;
  for (int i = tid; i < CV; i += 1024) bins[i] = 0;
  __syncthreads();
#pragma unroll
  for (int i = 0; i < 4; ++i) atomicAdd(&bins[ids[i * 1024 + tid]], 1);
  __syncthreads();
  unsigned b0 = 0, b1 = 0, b2 = 0, b3 = 0, b4 = 0;
  for (int i = tid; i < CV; i += 1024) {
    unsigned key = (((unsigned)bins[i]) << 15) | (unsigned)(32767 - i);
    chain5(key, b0, b1, b2, b3, b4);
  }
  l5[tid] = b0; l5[1024 + tid] = b1; l5[2048 + tid] = b2; l5[3072 + tid] = b3; l5[4096 + tid] = b4;
  __syncthreads();
  if (tid < 64) {
    unsigned c0 = 0, c1 = 0, c2 = 0, c3 = 0, c4 = 0;
    for (int i = tid; i < 5120; i += 64) chain5(l5[i], c0, c1, c2, c3, c4);
    w5[tid] = c0; w5[64 + tid] = c1; w5[128 + tid] = c2; w5[192 + tid] = c3; w5[256 + tid] = c4;
  }
  __syncthreads();
  if (tid == 0) {
    unsigned c0 = 0, c1 = 0, c2 = 0, c3 = 0, c4 = 0;
    for (int i = 0; i < 320; ++i) chain5(w5[i], c0, c1, c2, c3, c4);
    fin[0] = c0; fin[1] = c1; fin[2] = c2; fin[3] = c3; fin[4] = c4;
  }
  __syncthreads();
  {
    int cnt = bins[tid];
    float g = cnt > 0 ? 0.6f : 1.0f;
    unsigned key = (((unsigned)cnt) << 15) | (unsigned)(32767 - tid);
    if (key == fin[0] || key == fin[1] || key == fin[2] || key == fin[3] || key == fin[4])
      g = 1.5f;
    gains[tid] = g;
  }
}

// ---------------- fused: weights fp32->bf16 (blocks 0-4095) + token-shift mix (4096-8191) ----
__device__ __forceinline__ unsigned short mix1(float tm, float g, float xc, float px) {
  float m = tm * g;
  return f2bf(m * xc + (1.f - m) * px);
}

__global__ void nsr_cvtw_mix(const float* __restrict__ Wr, const float* __restrict__ Wk,
                             const float* __restrict__ Wv, const float* __restrict__ Wo,
                             unsigned short* __restrict__ dst, const float* __restrict__ x,
                             const float* __restrict__ gains, const float* __restrict__ tmr,
                             const float* __restrict__ tmk, const float* __restrict__ tmv,
                             unsigned short* __restrict__ xr, unsigned short* __restrict__ xk,
                             unsigned short* __restrict__ xv) {
  int bid = blockIdx.x;
  if (bid < 4096) {
    int i = bid * 256 + threadIdx.x;
    int which = i >> 18;
    int j = (i & 0x3FFFF) << 2;
    const float* s = which == 0 ? Wr : which == 1 ? Wk : which == 2 ? Wv : Wo;
    float4 v = *(const float4*)(s + j);
    ushort4 o = make_ushort4(f2bf(v.x), f2bf(v.y), f2bf(v.z), f2bf(v.w));
    *(ushort4*)(dst + (size_t)which * (CD * CD) + j) = o;
  } else {
    int i = (bid - 4096) * 256 + threadIdx.x;
    int m = i >> 8;
    int d = (i & 255) << 2;
    int t = m & (CT - 1);
    size_t base = (size_t)m * CD + d;
    float4 xc = *(const float4*)(x + base);
    float4 px = make_float4(0.f, 0.f, 0.f, 0.f);
    if (t > 0) px = *(const float4*)(x + base - CD);
    float4 g = *(const float4*)(gains + d);
    float4 ar = *(const float4*)(tmr + d);
    float4 ak = *(const float4*)(tmk + d);
    float4 av = *(const float4*)(tmv + d);
    *(ushort4*)(xr + base) = make_ushort4(mix1(ar.x, g.x, xc.x, px.x), mix1(ar.y, g.y, xc.y, px.y),
                                          mix1(ar.z, g.z, xc.z, px.z), mix1(ar.w, g.w, xc.w, px.w));
    *(ushort4*)(xk + base) = make_ushort4(mix1(ak.x, g.x, xc.x, px.x), mix1(ak.y, g.y, xc.y, px.y),
                                          mix1(ak.z, g.z, xc.z, px.z), mix1(ak.w, g.w, xc.w, px.w));
    *(ushort4*)(xv + base) = make_ushort4(mix1(av.x, g.x, xc.x, px.x), mix1(av.y, g.y, xc.y, px.y),
                                          mix1(av.z, g.z, xc.z, px.z), mix1(av.w, g.w, xc.w, px.w));
  }
}

// XCD-aware tile swizzle for 256-block GEMMs: dispatch round-robins bid over 8 XCDs,
// so give each XCD 4 m-tiles x 8 n-tiles -> A m-tile read once per chip into that
// XCD's L2 and reused by its 8 co-resident n-blocks.
__device__ __forceinline__ void swz_tiles(int bl, int& m0, int& n0) {
  int xcd = bl & 7, idx = bl >> 3;
  int mt8 = xcd * 4 + (idx & 3);
  int nt8 = idx >> 2;
  m0 = mt8 << 7;
  n0 = nt8 << 7;
}

// ---------------- 128x128 NT-GEMM core, DOUBLE-BUFFERED staging ----------------
// S = 4 x 4096-ushort banks: [As0][Bs0][As1][Bs1] (32KB). One barrier per K-iter;
// loads for k+1 are issued before consuming k, so they overlap the MFMA phase.
__device__ __forceinline__ void gemm128_db(const unsigned short* __restrict__ A,
                                           const unsigned short* __restrict__ W, int m0, int n0,
                                           int Klen, int ld, int tid, f32x4 acc[4][4],
                                           unsigned short* S) {
  const f32x4 fz = {0.f, 0.f, 0.f, 0.f};
  int lane = tid & 63, w = tid >> 6;
  int wm = (w >> 1) << 6, wn = (w & 1) << 6;
  int l15 = lane & 15, quad = lane >> 4;
#pragma unroll
  for (int mt = 0; mt < 4; ++mt)
#pragma unroll
    for (int nt = 0; nt < 4; ++nt) acc[mt][nt] = fz;

  // per-thread staging source/dest (chunk geometry fixed; only k0/buf vary)
  int r0 = tid >> 2, cp0 = tid & 3, c0 = cp0 ^ (r0 & 3);
  int r1 = (256 + tid) >> 2, cp1 = tid & 3, c1 = cp1 ^ (r1 & 3);
  const unsigned short* a0 = A + (size_t)(m0 + r0) * ld + c0 * 8;
  const unsigned short* a1 = A + (size_t)(m0 + r1) * ld + c1 * 8;
  const unsigned short* w0 = W + (size_t)(n0 + r0) * ld + c0 * 8;
  const unsigned short* w1 = W + (size_t)(n0 + r1) * ld + c1 * 8;
  int ldso0 = (tid & ~63) << 3;            // 0..1536
  int ldso1 = ((256 + tid) & ~63) << 3;    // 2048..3584

  // prime buffer 0
  lds_cp16(a0, &S[ldso0]);
  lds_cp16(w0, &S[4096 + ldso0]);
  lds_cp16(a1, &S[ldso1]);
  lds_cp16(w1, &S[4096 + ldso1]);

  for (int k0 = 0; k0 < Klen; k0 += 32) {
    int cur = (k0 >> 5) & 1;
    unsigned short* Sc = S + cur * 8192;
    __syncthreads();  // cur's loads complete; prev iter's ds_reads complete
    if (k0 + 32 < Klen) {
      unsigned short* Sn = S + (cur ^ 1) * 8192;
      int kn = k0 + 32;
      lds_cp16(a0 + kn, &Sn[ldso0]);
      lds_cp16(w0 + kn, &Sn[4096 + ldso0]);
      lds_cp16(a1 + kn, &Sn[ldso1]);
      lds_cp16(w1 + kn, &Sn[4096 + ldso1]);
    }
    s16x8 af[4], bf[4];
#pragma unroll
    for (int mt = 0; mt < 4; ++mt) {
      int row = wm + mt * 16 + l15;
      af[mt] = *(const s16x8*)&Sc[row * 32 + ((quad ^ (row & 3)) << 3)];
    }
#pragma unroll
    for (int nt = 0; nt < 4; ++nt) {
      int row = wn + nt * 16 + l15;
      bf[nt] = *(const s16x8*)&Sc[4096 + row * 32 + ((quad ^ (row & 3)) << 3)];
    }
#pragma unroll
    for (int mt = 0; mt < 4; ++mt)
#pragma unroll
      for (int nt = 0; nt < 4; ++nt)
        acc[mt][nt] = __builtin_amdgcn_mfma_f32_16x16x32_bf16(af[mt], bf[nt], acc[mt][nt], 0, 0, 0);
  }
}

// fused r/k/v projections; which==2 (v) writes TRANSPOSED vt[B,H,Dh,T] via LDS tile
// that OVERLAYS the (dead after K-loop) staging buffers.
__global__ __launch_bounds__(256) void nsr_proj(const unsigned short* __restrict__ xr,
                                                const unsigned short* __restrict__ xk,
                                                const unsigned short* __restrict__ xv,
                                                const unsigned short* __restrict__ Wb,
                                                unsigned short* __restrict__ r,
                                                unsigned short* __restrict__ k,
                                                unsigned short* __restrict__ vt) {
  __shared__ alignas(16) unsigned short smem[128 * 136];  // 34.8KB: staging (32KB) / vts overlay
  int bid = blockIdx.x;
  int which = bid >> 8;
  int m0, n0;
  swz_tiles(bid & 255, m0, n0);
  const unsigned short* A = which == 0 ? xr : which == 1 ? xk : xv;
  const unsigned short* W = Wb + (size_t)which * (CD * CD);
  f32x4 acc[4][4];
  gemm128_db(A, W, m0, n0, CD, CD, threadIdx.x, acc, smem);
  int tid = threadIdx.x;
  int lane = tid & 63, w = tid >> 6;
  int wm = (w >> 1) << 6, wn = (w & 1) << 6;
  int l15 = lane & 15, quad = lane >> 4;
  if (which < 2) {
    unsigned short* out = which == 0 ? r : k;
#pragma unroll
    for (int mt = 0; mt < 4; ++mt)
#pragma unroll
      for (int nt = 0; nt < 4; ++nt)
#pragma unroll
        for (int rr = 0; rr < 4; ++rr) {
          int grow = m0 + wm + mt * 16 + quad * 4 + rr;
          int gcol = n0 + wn + nt * 16 + l15;
          float val = acc[mt][nt][rr];
          if (which == 1) val = val > 0.5f ? 1.0f : 0.0f;  // spike forward
          out[(size_t)grow * CD + gcol] = f2bf(val);
        }
  } else {
    unsigned short* vts = smem;
    __syncthreads();  // all waves done reading staging before overlay write
    // stage C^T into vts[d_local][t_local] (stride 136: 2-way-free b64 writes)
#pragma unroll
    for (int mt = 0; mt < 4; ++mt)
#pragma unroll
      for (int nt = 0; nt < 4; ++nt) {
        int gcl = wn + nt * 16 + l15;       // d-local 0..127
        int gr = wm + mt * 16 + quad * 4;   // t-local, multiple of 4
        unsigned lo = pkrh(acc[mt][nt][0], acc[mt][nt][1]);
        unsigned hi = pkrh(acc[mt][nt][2], acc[mt][nt][3]);
        uint2 pk = make_uint2(lo, hi);
        *(uint2*)&vts[gcl * 136 + gr] = pk;
      }
    __syncthreads();
    // coalesced write-out: 16 lanes cover one full 256B vt row per instruction
    int b2 = m0 >> 11, t0 = m0 & (CT - 1);
    int ch = tid & 15, dl2 = tid >> 4;  // ch: t-chunk 0..15, dl2: d 0..15
#pragma unroll
    for (int rr2 = 0; rr2 < 8; ++rr2) {
      int dloc = rr2 * 16 + dl2;
      int h = (n0 + dloc) >> 6, dl = (n0 + dloc) & 63;
      s16x8 val = *(const s16x8*)&vts[dloc * 136 + ch * 8];
      size_t ob = ((size_t)((b2 * CH + h) * CDh + dl)) * CT + t0 + ch * 8;
      *(s16x8*)(vt + ob) = val;
    }
  }
}

// ---------------- fused attention + sigmoid gating (S^T formulation, q-tile 128) --------
// 8 waves: qh = w&3 (32-q subtile), kq2 = w>>2 (key half). S^T = K·Q^T (32x32x16).
// C->B transform via v_permlane32_swap_b32 (gfx950): swap(P01,P45) = {br0, br2}.
__global__ __launch_bounds__(512, 2) void nsr_attn(const unsigned short* __restrict__ rbf,
                                                   const unsigned short* __restrict__ kbf,
                                                   const unsigned short* __restrict__ vt,
                                                   unsigned short* __restrict__ gated) {
  __shared__ alignas(16) unsigned char smem[32768];
  __shared__ float denp[2][128];
  unsigned short* Ks = (unsigned short*)smem;            // 16KB [128 key][64 d] swizzled
  unsigned short* Vs = (unsigned short*)(smem + 16384);  // 16KB [64 d][128 key] swizzled
  float* Ored = (float*)smem;  // 32KB overlay [qh(4)][d(64)][q31(32)], used after kt loop

  const f32x16 fz16 = {0.f, 0.f, 0.f, 0.f, 0.f, 0.f, 0.f, 0.f,
                       0.f, 0.f, 0.f, 0.f, 0.f, 0.f, 0.f, 0.f};
  const float EXSC = 0.125f * 1.44269504088896f;  // exp(x/8) = exp2(x*EXSC)
  int bid = blockIdx.x;
  int b = bid & 1, hd = (bid >> 1) & 15, qt = bid >> 5;
  int tid = threadIdx.x, lane = tid & 63, w = tid >> 6;
  int l31 = lane & 31, hbit = lane >> 5;
  int qh = w & 3, kq2 = w >> 2;

  // Q fragments from global, pre-scaled by EXSC in registers
  const unsigned short* qrow = rbf + (size_t)(b * CT + qt * 128 + qh * 32 + l31) * CD + hd * 64;
  s16x8 qfrag[4];
#pragma unroll
  for (int s4 = 0; s4 < 4; ++s4) {
    s16x8 qf = *(const s16x8*)(qrow + s4 * 16 + hbit * 8);
    unsigned* qd = (unsigned*)&qf;
#pragma unroll
    for (int j = 0; j < 4; ++j) {
      float lo = __builtin_bit_cast(float, qd[j] << 16) * EXSC;
      float hi = __builtin_bit_cast(float, qd[j] & 0xFFFF0000u) * EXSC;
      qd[j] = pkrh(lo, hi);
    }
    qfrag[s4] = qf;
  }

  // precomputed LDS fragment addresses (kt-invariant)
  const unsigned short* kap[2][4];
#pragma unroll
  for (int ktile = 0; ktile < 2; ++ktile) {
    int keyrow = kq2 * 64 + ktile * 32 + l31;
#pragma unroll
    for (int s4 = 0; s4 < 4; ++s4) {
      int cp = (s4 * 2 + hbit) ^ (keyrow & 7);
      kap[ktile][s4] = &Ks[keyrow * 64 + cp * 8];
    }
  }
  const unsigned short* vap[2][2][2];
#pragma unroll
  for (int ktile = 0; ktile < 2; ++ktile)
#pragma unroll
    for (int s = 0; s < 2; ++s)
#pragma unroll
      for (int dt = 0; dt < 2; ++dt) {
        int drow = dt * 32 + l31;
        int c = kq2 * 8 + ktile * 4 + s * 2 + hbit;
        int cp = (c & 8) | ((c ^ drow) & 7);
        vap[ktile][s][dt] = &Vs[drow * 128 + cp * 8];
      }

  // precomputed staging pointers (advance by constant stride per kt)
  const unsigned short* kgp[2];
  const unsigned short* vgp[2];
  unsigned short* ldk[2];
  unsigned short* ldv[2];
  {
    const unsigned short* kgbase = kbf + (size_t)(b * CT) * CD + hd * 64;
    const unsigned short* vgbase = vt + (size_t)((b * CH + hd) * CDh) * CT;
#pragma unroll
    for (int i = 0; i < 2; ++i) {
      int L = i * 512 + tid;
      int key = L >> 3, cpk = (L & 7) ^ (key & 7);
      kgp[i] = kgbase + (size_t)key * CD + cpk * 8;
      ldk[i] = &Ks[(L & ~63) << 3];
      int d = L >> 4, cp2 = L & 15, c2 = (cp2 & 8) | ((cp2 ^ d) & 7);
      vgp[i] = vgbase + (size_t)d * CT + c2 * 8;
      ldv[i] = &Vs[(L & ~63) << 3];
    }
  }

  f32x16 o_acc[2];
  o_acc[0] = fz16;
  o_acc[1] = fz16;
  float den0 = 0.f, den1 = 0.f;

  for (int kt = 0; kt < 16; ++kt) {
#pragma unroll
    for (int i = 0; i < 2; ++i) {
      lds_cp16(kgp[i], ldk[i]);
      lds_cp16(vgp[i], ldv[i]);
      kgp[i] += 128 * CD;
      vgp[i] += 128;
    }
    __syncthreads();

#pragma unroll
    for (int ktile = 0; ktile < 2; ++ktile) {
      f32x16 sc = fz16;
#pragma unroll
      for (int s4 = 0; s4 < 4; ++s4)
        sc = __builtin_amdgcn_mfma_f32_32x32x16_bf16(*(const s16x8*)kap[ktile][s4], qfrag[s4], sc,
                                                     0, 0, 0);
#pragma unroll
      for (int s = 0; s < 2; ++s) {
        int rb = 8 * s;
        float p0 = __builtin_amdgcn_exp2f(sc[rb + 0]);
        float p1 = __builtin_amdgcn_exp2f(sc[rb + 1]);
        float p2 = __builtin_amdgcn_exp2f(sc[rb + 2]);
        float p3 = __builtin_amdgcn_exp2f(sc[rb + 3]);
        float p4 = __builtin_amdgcn_exp2f(sc[rb + 4]);
        float p5 = __builtin_amdgcn_exp2f(sc[rb + 5]);
        float p6 = __builtin_amdgcn_exp2f(sc[rb + 6]);
        float p7 = __builtin_amdgcn_exp2f(sc[rb + 7]);
        den0 += (p0 + p1) + (p2 + p3);
        den1 += (p4 + p5) + (p6 + p7);
        unsigned P01 = pkrh(p0, p1), P23 = pkrh(p2, p3);
        unsigned P45 = pkrh(p4, p5), P67 = pkrh(p6, p7);
        unsigned br[4];
#if __has_builtin(__builtin_amdgcn_permlane32_swap)
        u32x2 sw0 = __builtin_amdgcn_permlane32_swap(P01, P45, false, false);
        u32x2 sw1 = __builtin_amdgcn_permlane32_swap(P23, P67, false, false);
        br[0] = sw0.x; br[2] = sw0.y;
        br[1] = sw1.x; br[3] = sw1.y;
#else
        unsigned send0 = hbit ? P01 : P45;
        unsigned send1 = hbit ? P23 : P67;
        unsigned recv0 = (unsigned)__shfl_xor((int)send0, 32);
        unsigned recv1 = (unsigned)__shfl_xor((int)send1, 32);
        br[0] = hbit ? recv0 : P01;
        br[1] = hbit ? recv1 : P23;
        br[2] = hbit ? P45 : recv0;
        br[3] = hbit ? P67 : recv1;
#endif
        s16x8 bfrag = __builtin_bit_cast(s16x8, *(const unsigned(*)[4])br);
        o_acc[0] = __builtin_amdgcn_mfma_f32_32x32x16_bf16(*(const s16x8*)vap[ktile][s][0], bfrag,
                                                           o_acc[0], 0, 0, 0);
        o_acc[1] = __builtin_amdgcn_mfma_f32_32x32x16_bf16(*(const s16x8*)vap[ktile][s][1], bfrag,
                                                           o_acc[1], 0, 0, 0);
      }
    }
    __syncthreads();
  }

  // den: the two lane-halves covered complementary keys
  float den = den0 + den1;
  den += __shfl_xor(den, 32);
  if (hbit == 0) denp[kq2][qh * 32 + l31] = den;
  __syncthreads();
  float rinv = 1.0f / (denp[0][qh * 32 + l31] + denp[1][qh * 32 + l31]);

  // cross-wave O reduction (key-half pairs) through the 32KB Ored overlay
  if (kq2 == 1) {
#pragma unroll
    for (int dt = 0; dt < 2; ++dt)
#pragma unroll
      for (int rr = 0; rr < 16; ++rr) {
        int d = dt * 32 + (rr & 3) + 8 * (rr >> 2) + 4 * hbit;
        Ored[qh * 2048 + d * 32 + l31] = o_acc[dt][rr];
      }
  }
  __syncthreads();
  if (kq2 == 0) {
#pragma unroll
    for (int dt = 0; dt < 2; ++dt)
#pragma unroll
      for (int rr = 0; rr < 16; ++rr) {
        int d = dt * 32 + (rr & 3) + 8 * (rr >> 2) + 4 * hbit;
        int idx = qh * 2048 + d * 32 + l31;
        Ored[idx] = (o_acc[dt][rr] + Ored[idx]) * rinv;
      }
  }
  __syncthreads();

  // coalesced epilogue: sigmoid(r) gating + bf16 store
  int q = tid >> 2, dc = tid & 3;
  size_t grow = (size_t)(b * CT + qt * 128 + q) * CD + hd * 64 + dc * 16;
  s16x8 rv0 = *(const s16x8*)(rbf + grow);
  s16x8 rv1 = *(const s16x8*)(rbf + grow + 8);
  unsigned short outv[16];
#pragma unroll
  for (int i = 0; i < 16; ++i) {
    float o = Ored[(q >> 5) * 2048 + (dc * 16 + i) * 32 + (q & 31)];
    float rv = bf2f(i < 8 ? ((unsigned short*)&rv0)[i] : ((unsigned short*)&rv1)[i - 8]);
    float sig = 1.f / (1.f + __expf(-rv));
    outv[i] = f2bf(sig * o);
  }
  *(s16x8*)(gated + grow) = *(s16x8*)&outv[0];
  *(s16x8*)(gated + grow + 8) = *(s16x8*)&outv[8];
}

// ---------------- output GEMM: out = gated @ Wo^T + bo (fp32 out) ----------------
__global__ __launch_bounds__(256) void nsr_out(const unsigned short* __restrict__ gated,
                                               const unsigned short* __restrict__ Wo,
                                               const float* __restrict__ bo,
                                               float* __restrict__ out) {
  __shared__ alignas(16) unsigned short smem[4 * 4096];  // 32KB dbuf staging
  int m0, n0;
  swz_tiles(blockIdx.x, m0, n0);
  f32x4 acc[4][4];
  gemm128_db(gated, Wo, m0, n0, CD, CD, threadIdx.x, acc, smem);
  int lane = threadIdx.x & 63, w = threadIdx.x >> 6;
  int wm = (w >> 1) << 6, wn = (w & 1) << 6;
  int l15 = lane & 15, quad = lane >> 4;
#pragma unroll
  for (int mt = 0; mt < 4; ++mt)
#pragma unroll
    for (int nt = 0; nt < 4; ++nt)
#pragma unroll
      for (int rr = 0; rr < 4; ++rr) {
        int grow = m0 + wm + mt * 16 + quad * 4 + rr;
        int gcol = n0 + wn + nt * 16 + l15;
        out[(size_t)grow * CD + gcol] = acc[mt][nt][rr] + bo[gcol];
      }
}

extern "C" void kernel_launch(void* const* d_in, const int* in_sizes, int n_in,
                              void* d_out, int out_size, void* d_ws, size_t ws_size,
                              hipStream_t stream) {
  const float* x = (const float*)d_in[0];
  const int* ids = (const int*)d_in[1];
  const float* Wr = (const float*)d_in[2];
  const float* Wk = (const float*)d_in[3];
  const float* Wv = (const float*)d_in[4];
  const float* Wo = (const float*)d_in[5];
  const float* bo = (const float*)d_in[6];
  const float* tmk = (const float*)d_in[7];
  const float* tmv = (const float*)d_in[8];
  const float* tmr = (const float*)d_in[9];

  char* ws = (char*)d_ws;
  size_t off = 0;
  int* bins = (int*)(ws + off); off += 131072;
  float* gains = (float*)(ws + off); off += 4096;
  unsigned short* Wb = (unsigned short*)(ws + off); off += (size_t)4 * CD * CD * 2;
  unsigned short* xr = (unsigned short*)(ws + off); off += (size_t)CM * CD * 2;
  unsigned short* xk = (unsigned short*)(ws + off); off += (size_t)CM * CD * 2;
  unsigned short* xv = (unsigned short*)(ws + off); off += (size_t)CM * CD * 2;
  unsigned short* rb = (unsigned short*)(ws + off); off += (size_t)CM * CD * 2;
  unsigned short* kb = (unsigned short*)(ws + off); off += (size_t)CM * CD * 2;
  unsigned short* vtb = (unsigned short*)(ws + off); off += (size_t)CM * CD * 2;
  unsigned short* gatedb = (unsigned short*)(ws + off); off += (size_t)CM * CD * 2;

  nsr_gains<<<1, 1024, 0, stream>>>(ids, bins, gains);
  nsr_cvtw_mix<<<8192, 256, 0, stream>>>(Wr, Wk, Wv, Wo, Wb, x, gains, tmr, tmk, tmv, xr, xk, xv);
  nsr_proj<<<768, 256, 0, stream>>>(xr, xk, xv, Wb, rb, kb, vtb);
  nsr_attn<<<512, 512, 0, stream>>>(rb, kb, vtb, gatedb);
  nsr_out<<<256, 256, 0, stream>>>(gatedb, Wb + (size_t)3 * CD * CD, bo, (float*)d_out);
}